// Round 1
// baseline (1508.792 us; speedup 1.0000x reference)
//
#include <hip/hip_runtime.h>
#include <hip/hip_bf16.h>

typedef __bf16 bf16;
typedef bf16 bf16x8 __attribute__((ext_vector_type(8)));
typedef bf16 bf16x4 __attribute__((ext_vector_type(4)));
typedef float f32x4 __attribute__((ext_vector_type(4)));

constexpr int NN = 30000;
constexpr int NE = 600000;
constexpr int D  = 128;

__device__ inline f32x4 mfma16(bf16x8 a, bf16x8 b, f32x4 c) {
    return __builtin_amdgcn_mfma_f32_16x16x32_bf16(a, b, c, 0, 0, 0);
}

__device__ inline bf16x8 ld8(const bf16* p) {
    return *reinterpret_cast<const bf16x8*>(p);
}

__device__ inline bf16x8 cvt8(const float* p) {
    float4 v0 = reinterpret_cast<const float4*>(p)[0];
    float4 v1 = reinterpret_cast<const float4*>(p)[1];
    bf16x8 r;
    r[0] = (bf16)v0.x; r[1] = (bf16)v0.y; r[2] = (bf16)v0.z; r[3] = (bf16)v0.w;
    r[4] = (bf16)v1.x; r[5] = (bf16)v1.y; r[6] = (bf16)v1.z; r[7] = (bf16)v1.w;
    return r;
}

// swizzled LDS byte offsets: rows of 512B (256 bf16) / 256B (128 bf16)
__device__ inline int swz512(int row, int byteInRow) {
    return row * 512 + (byteInRow ^ ((row & 15) << 4));
}
__device__ inline int swz256(int row, int byteInRow) {
    return row * 256 + (byteInRow ^ ((row & 15) << 4));
}

// ---------------------------------------------------------------- prep kernels
struct TMat { const float* src; bf16* dst; int K; int Nc; };
struct TPack { TMat m[8]; };

// WT[c][k] = W[k][c], cast to bf16.  dst is [Nc][K] row-major.
__global__ void transpose_cast_kernel(TPack p) {
    TMat mm = p.m[blockIdx.x];
    int total = mm.K * mm.Nc;
    for (int idx = blockIdx.y * blockDim.x + threadIdx.x; idx < total;
         idx += gridDim.y * blockDim.x) {
        int c = idx / mm.K;
        int k = idx - c * mm.K;
        mm.dst[idx] = (bf16)mm.src[k * mm.Nc + c];
    }
}

__global__ void cast_nf_kernel(const float* __restrict__ src, bf16* __restrict__ dst) {
    int i = blockIdx.x * blockDim.x + threadIdx.x;   // one float4 per thread
    if (i < NN * D / 4) {
        float4 v = reinterpret_cast<const float4*>(src)[i];
        bf16x4 o;
        o[0] = (bf16)v.x; o[1] = (bf16)v.y; o[2] = (bf16)v.z; o[3] = (bf16)v.w;
        reinterpret_cast<bf16x4*>(dst)[i] = o;
    }
}

// ---------------------------------------------------------------- edge MLP
// edge_feat = relu([h[src], nf[src], nf[dst]] @ W_e1 + b_e1) @ W_e2 + b_e2
// h_out[dst] += edge_feat   (fp32 atomics)
template<bool HAS_H>
__global__ void __launch_bounds__(256, 2)
edge_mlp_kernel(const bf16* __restrict__ nf_bf,
                const float* __restrict__ h_prev,
                const int* __restrict__ src,
                const int* __restrict__ dst,
                const bf16* __restrict__ We1T,   // [256][384]
                const bf16* __restrict__ We2T,   // [128][256]
                const float* __restrict__ b_e1,
                const float* __restrict__ b_e2,
                float* __restrict__ h_out)
{
    __shared__ int s_src[64];
    __shared__ int s_dst[64];
    __shared__ __align__(16) char sH[64 * 512];

    const int t  = threadIdx.x;
    const int wv = t >> 6;
    const int l  = t & 63;
    const int lr = l & 15;
    const int qk = l >> 4;
    const int e0 = blockIdx.x * 64;

    if (t < 64)       s_src[t]      = src[e0 + t];
    else if (t < 128) s_dst[t - 64] = dst[e0 + (t - 64)];
    __syncthreads();

    const bf16*  pS[4];
    const bf16*  pD[4];
    const float* pH[4];
#pragma unroll
    for (int m = 0; m < 4; ++m) {
        int e = m * 16 + lr;
        pS[m] = nf_bf + s_src[e] * D;
        pD[m] = nf_bf + s_dst[e] * D;
        if constexpr (HAS_H) pH[m] = h_prev + s_src[e] * D;
    }

    int coln[4];
#pragma unroll
    for (int n = 0; n < 4; ++n) coln[n] = wv * 64 + n * 16 + lr;

    f32x4 acc[4][4];
#pragma unroll
    for (int m = 0; m < 4; ++m)
#pragma unroll
        for (int n = 0; n < 4; ++n) acc[m][n] = 0.f;

    // ---- layer 1: K = (HAS_H ? 384 : 256), 32-wide k-steps
#pragma unroll
    for (int ks = 0; ks < 4; ++ks) {
        const int kg = ks * 32 + qk * 8;
        bf16x8 a[4], b[4];
        if constexpr (HAS_H) {
#pragma unroll
            for (int m = 0; m < 4; ++m) a[m] = cvt8(pH[m] + kg);
#pragma unroll
            for (int n = 0; n < 4; ++n) b[n] = ld8(We1T + coln[n] * 384 + kg);
#pragma unroll
            for (int m = 0; m < 4; ++m)
#pragma unroll
                for (int n = 0; n < 4; ++n) acc[m][n] = mfma16(a[m], b[n], acc[m][n]);
        }
        // segment: nf[src] (k 128..255)
#pragma unroll
        for (int m = 0; m < 4; ++m) a[m] = ld8(pS[m] + kg);
#pragma unroll
        for (int n = 0; n < 4; ++n) b[n] = ld8(We1T + coln[n] * 384 + 128 + kg);
#pragma unroll
        for (int m = 0; m < 4; ++m)
#pragma unroll
            for (int n = 0; n < 4; ++n) acc[m][n] = mfma16(a[m], b[n], acc[m][n]);
        // segment: nf[dst] (k 256..383)
#pragma unroll
        for (int m = 0; m < 4; ++m) a[m] = ld8(pD[m] + kg);
#pragma unroll
        for (int n = 0; n < 4; ++n) b[n] = ld8(We1T + coln[n] * 384 + 256 + kg);
#pragma unroll
        for (int m = 0; m < 4; ++m)
#pragma unroll
            for (int n = 0; n < 4; ++n) acc[m][n] = mfma16(a[m], b[n], acc[m][n]);
    }

    // bias + relu -> swizzled LDS [64][256] bf16
#pragma unroll
    for (int n = 0; n < 4; ++n) {
        float bia = b_e1[coln[n]];
#pragma unroll
        for (int m = 0; m < 4; ++m) {
#pragma unroll
            for (int j = 0; j < 4; ++j) {
                int row = m * 16 + qk * 4 + j;
                float v = acc[m][n][j] + bia;
                v = v > 0.f ? v : 0.f;
                *reinterpret_cast<bf16*>(sH + swz512(row, coln[n] * 2)) = (bf16)v;
            }
        }
    }
    __syncthreads();

    // ---- layer 2: [64,256] @ We2T -> [64,128]; wave owns 32 cols
    int col2[2];
#pragma unroll
    for (int n = 0; n < 2; ++n) col2[n] = wv * 32 + n * 16 + lr;
    f32x4 acc2[4][2];
#pragma unroll
    for (int m = 0; m < 4; ++m)
#pragma unroll
        for (int n = 0; n < 2; ++n) acc2[m][n] = 0.f;

#pragma unroll
    for (int ks = 0; ks < 8; ++ks) {
        const int k0 = ks * 32 + qk * 8;
        bf16x8 a[4], b[2];
#pragma unroll
        for (int m = 0; m < 4; ++m)
            a[m] = *reinterpret_cast<const bf16x8*>(sH + swz512(m * 16 + lr, k0 * 2));
#pragma unroll
        for (int n = 0; n < 2; ++n) b[n] = ld8(We2T + col2[n] * 256 + k0);
#pragma unroll
        for (int m = 0; m < 4; ++m)
#pragma unroll
            for (int n = 0; n < 2; ++n) acc2[m][n] = mfma16(a[m], b[n], acc2[m][n]);
    }

    // bias + scatter-add into h_out
#pragma unroll
    for (int n = 0; n < 2; ++n) {
        float bia = b_e2[col2[n]];
#pragma unroll
        for (int m = 0; m < 4; ++m) {
#pragma unroll
            for (int j = 0; j < 4; ++j) {
                int e = m * 16 + qk * 4 + j;
                float v = acc2[m][n][j] + bia;
                atomicAdd(h_out + s_dst[e] * D + col2[n], v);
            }
        }
    }
}

// ---------------------------------------------------------------- node MLP
// nf2 = relu([nf, h] @ W_n1 + b_n1) @ W_n2 + b_n2 ; n_out = nf2 @ W_nro + b_nro
__global__ void __launch_bounds__(256, 2)
node_mlp_kernel(const bf16* __restrict__ nf_bf,
                const float* __restrict__ hB,
                const bf16* __restrict__ Wn1T,   // [256][256]
                const bf16* __restrict__ Wn2T,   // [128][256]
                const bf16* __restrict__ WnroT,  // [128][128]
                const float* __restrict__ b_n1,
                const float* __restrict__ b_n2,
                const float* __restrict__ b_nro,
                bf16* __restrict__ nf2_bf,
                float* __restrict__ n_out)
{
    __shared__ __align__(16) char sH[64 * 512];

    const int t  = threadIdx.x;
    const int wv = t >> 6;
    const int l  = t & 63;
    const int lr = l & 15;
    const int qk = l >> 4;
    const int r0 = blockIdx.x * 64;

    const bf16*  pN[4];
    const float* pH[4];
#pragma unroll
    for (int m = 0; m < 4; ++m) {
        int r = r0 + m * 16 + lr;
        r = r < NN ? r : NN - 1;
        pN[m] = nf_bf + r * D;
        pH[m] = hB + r * D;
    }

    int coln[4];
#pragma unroll
    for (int n = 0; n < 4; ++n) coln[n] = wv * 64 + n * 16 + lr;

    f32x4 acc[4][4];
#pragma unroll
    for (int m = 0; m < 4; ++m)
#pragma unroll
        for (int n = 0; n < 4; ++n) acc[m][n] = 0.f;

#pragma unroll
    for (int ks = 0; ks < 4; ++ks) {
        const int kg = ks * 32 + qk * 8;
        bf16x8 a[4], b[4];
#pragma unroll
        for (int m = 0; m < 4; ++m) a[m] = ld8(pN[m] + kg);
#pragma unroll
        for (int n = 0; n < 4; ++n) b[n] = ld8(Wn1T + coln[n] * 256 + kg);
#pragma unroll
        for (int m = 0; m < 4; ++m)
#pragma unroll
            for (int n = 0; n < 4; ++n) acc[m][n] = mfma16(a[m], b[n], acc[m][n]);
#pragma unroll
        for (int m = 0; m < 4; ++m) a[m] = cvt8(pH[m] + kg);
#pragma unroll
        for (int n = 0; n < 4; ++n) b[n] = ld8(Wn1T + coln[n] * 256 + 128 + kg);
#pragma unroll
        for (int m = 0; m < 4; ++m)
#pragma unroll
            for (int n = 0; n < 4; ++n) acc[m][n] = mfma16(a[m], b[n], acc[m][n]);
    }

#pragma unroll
    for (int n = 0; n < 4; ++n) {
        float bia = b_n1[coln[n]];
#pragma unroll
        for (int m = 0; m < 4; ++m) {
#pragma unroll
            for (int j = 0; j < 4; ++j) {
                int row = m * 16 + qk * 4 + j;
                float v = acc[m][n][j] + bia;
                v = v > 0.f ? v : 0.f;
                *reinterpret_cast<bf16*>(sH + swz512(row, coln[n] * 2)) = (bf16)v;
            }
        }
    }
    __syncthreads();

    int col2[2];
#pragma unroll
    for (int n = 0; n < 2; ++n) col2[n] = wv * 32 + n * 16 + lr;
    f32x4 acc2[4][2];
#pragma unroll
    for (int m = 0; m < 4; ++m)
#pragma unroll
        for (int n = 0; n < 2; ++n) acc2[m][n] = 0.f;

#pragma unroll
    for (int ks = 0; ks < 8; ++ks) {
        const int k0 = ks * 32 + qk * 8;
        bf16x8 a[4], b[2];
#pragma unroll
        for (int m = 0; m < 4; ++m)
            a[m] = *reinterpret_cast<const bf16x8*>(sH + swz512(m * 16 + lr, k0 * 2));
#pragma unroll
        for (int n = 0; n < 2; ++n) b[n] = ld8(Wn2T + col2[n] * 256 + k0);
#pragma unroll
        for (int m = 0; m < 4; ++m)
#pragma unroll
            for (int n = 0; n < 2; ++n) acc2[m][n] = mfma16(a[m], b[n], acc2[m][n]);
    }
    __syncthreads();   // all reads of sH done before overlay

    // nf2 (no relu): to global bf16 + LDS (overlay sH as [64][128] bf16)
#pragma unroll
    for (int n = 0; n < 2; ++n) {
        float bia = b_n2[col2[n]];
#pragma unroll
        for (int m = 0; m < 4; ++m) {
#pragma unroll
            for (int j = 0; j < 4; ++j) {
                int row = m * 16 + qk * 4 + j;
                int gr  = r0 + row;
                float v = acc2[m][n][j] + bia;
                bf16 bv = (bf16)v;
                *reinterpret_cast<bf16*>(sH + swz256(row, col2[n] * 2)) = bv;
                if (gr < NN) nf2_bf[gr * D + col2[n]] = bv;
            }
        }
    }
    __syncthreads();

    // readout: n_out = nf2 @ WnroT^T + b_nro (K=128)
    f32x4 acc3[4][2];
#pragma unroll
    for (int m = 0; m < 4; ++m)
#pragma unroll
        for (int n = 0; n < 2; ++n) acc3[m][n] = 0.f;
#pragma unroll
    for (int ks = 0; ks < 4; ++ks) {
        const int k0 = ks * 32 + qk * 8;
        bf16x8 a[4], b[2];
#pragma unroll
        for (int m = 0; m < 4; ++m)
            a[m] = *reinterpret_cast<const bf16x8*>(sH + swz256(m * 16 + lr, k0 * 2));
#pragma unroll
        for (int n = 0; n < 2; ++n) b[n] = ld8(WnroT + col2[n] * D + k0);
#pragma unroll
        for (int m = 0; m < 4; ++m)
#pragma unroll
            for (int n = 0; n < 2; ++n) acc3[m][n] = mfma16(a[m], b[n], acc3[m][n]);
    }
#pragma unroll
    for (int n = 0; n < 2; ++n) {
        float bia = b_nro[col2[n]];
#pragma unroll
        for (int m = 0; m < 4; ++m) {
#pragma unroll
            for (int j = 0; j < 4; ++j) {
                int gr = r0 + m * 16 + qk * 4 + j;
                if (gr < NN) n_out[gr * D + col2[n]] = acc3[m][n][j] + bia;
            }
        }
    }
}

// ---------------------------------------------------------------- edge logits
// comb = (relu(s@Wt+d@Wb+b1) + relu(d@Wt+s@Wb+b1)) @ W_el2 + 2*b_el2
// e_ro = comb @ W_ero + b_ero ; e_lg = comb @ W_logit + b_logit
__global__ void __launch_bounds__(256, 2)
edge_logit_kernel(const bf16* __restrict__ nf2_bf,
                  const int* __restrict__ src,
                  const int* __restrict__ dst,
                  const bf16* __restrict__ Wel1T,  // [256][256]
                  const bf16* __restrict__ Wel2T,  // [128][256]
                  const bf16* __restrict__ WeroT,  // [128][128]
                  const float* __restrict__ W_logit, // [128][2] f32
                  const float* __restrict__ b_el1,
                  const float* __restrict__ b_el2,
                  const float* __restrict__ b_ero,
                  const float* __restrict__ b_logit,
                  float* __restrict__ e_ro,
                  float* __restrict__ e_lg)
{
    __shared__ int s_src[64];
    __shared__ int s_dst[64];
    __shared__ __align__(16) char sH[64 * 512];

    const int t  = threadIdx.x;
    const int wv = t >> 6;
    const int l  = t & 63;
    const int lr = l & 15;
    const int qk = l >> 4;
    const int e0 = blockIdx.x * 64;

    if (t < 64)       s_src[t]      = src[e0 + t];
    else if (t < 128) s_dst[t - 64] = dst[e0 + (t - 64)];
    __syncthreads();

    const bf16* pS[4];
    const bf16* pD[4];
#pragma unroll
    for (int m = 0; m < 4; ++m) {
        int e = m * 16 + lr;
        pS[m] = nf2_bf + s_src[e] * D;
        pD[m] = nf2_bf + s_dst[e] * D;
    }

    int coln[4];
#pragma unroll
    for (int n = 0; n < 4; ++n) coln[n] = wv * 64 + n * 16 + lr;

    f32x4 h1[4][4], h2[4][4];
#pragma unroll
    for (int m = 0; m < 4; ++m)
#pragma unroll
        for (int n = 0; n < 4; ++n) { h1[m][n] = 0.f; h2[m][n] = 0.f; }

    // layer 1, K=128 (shared gathers for both orders)
#pragma unroll
    for (int ks = 0; ks < 4; ++ks) {
        const int kg = ks * 32 + qk * 8;
        bf16x8 as[4], ad[4];
#pragma unroll
        for (int m = 0; m < 4; ++m) { as[m] = ld8(pS[m] + kg); ad[m] = ld8(pD[m] + kg); }
#pragma unroll
        for (int n = 0; n < 4; ++n) {
            bf16x8 bt = ld8(Wel1T + coln[n] * 256 + kg);
            bf16x8 bb = ld8(Wel1T + coln[n] * 256 + 128 + kg);
#pragma unroll
            for (int m = 0; m < 4; ++m) {
                h1[m][n] = mfma16(as[m], bt, h1[m][n]);
                h1[m][n] = mfma16(ad[m], bb, h1[m][n]);
                h2[m][n] = mfma16(ad[m], bt, h2[m][n]);
                h2[m][n] = mfma16(as[m], bb, h2[m][n]);
            }
        }
    }

    // relu(h1)+relu(h2) -> swizzled LDS [64][256]
#pragma unroll
    for (int n = 0; n < 4; ++n) {
        float bia = b_el1[coln[n]];
#pragma unroll
        for (int m = 0; m < 4; ++m) {
#pragma unroll
            for (int j = 0; j < 4; ++j) {
                int row = m * 16 + qk * 4 + j;
                float v1 = h1[m][n][j] + bia; v1 = v1 > 0.f ? v1 : 0.f;
                float v2 = h2[m][n][j] + bia; v2 = v2 > 0.f ? v2 : 0.f;
                *reinterpret_cast<bf16*>(sH + swz512(row, coln[n] * 2)) = (bf16)(v1 + v2);
            }
        }
    }
    __syncthreads();

    // layer 2: [64,256] @ Wel2T -> comb [64,128]
    int col2[2];
#pragma unroll
    for (int n = 0; n < 2; ++n) col2[n] = wv * 32 + n * 16 + lr;
    f32x4 acc2[4][2];
#pragma unroll
    for (int m = 0; m < 4; ++m)
#pragma unroll
        for (int n = 0; n < 2; ++n) acc2[m][n] = 0.f;

#pragma unroll
    for (int ks = 0; ks < 8; ++ks) {
        const int k0 = ks * 32 + qk * 8;
        bf16x8 a[4], b[2];
#pragma unroll
        for (int m = 0; m < 4; ++m)
            a[m] = *reinterpret_cast<const bf16x8*>(sH + swz512(m * 16 + lr, k0 * 2));
#pragma unroll
        for (int n = 0; n < 2; ++n) b[n] = ld8(Wel2T + col2[n] * 256 + k0);
#pragma unroll
        for (int m = 0; m < 4; ++m)
#pragma unroll
            for (int n = 0; n < 2; ++n) acc2[m][n] = mfma16(a[m], b[n], acc2[m][n]);
    }
    __syncthreads();   // all sH reads done

    // comb -> LDS overlay [64][128] bf16
#pragma unroll
    for (int n = 0; n < 2; ++n) {
        float bia = 2.f * b_el2[col2[n]];
#pragma unroll
        for (int m = 0; m < 4; ++m) {
#pragma unroll
            for (int j = 0; j < 4; ++j) {
                int row = m * 16 + qk * 4 + j;
                float v = acc2[m][n][j] + bia;
                *reinterpret_cast<bf16*>(sH + swz256(row, col2[n] * 2)) = (bf16)v;
            }
        }
    }
    __syncthreads();

    // readout: e_ro = comb @ WeroT^T + b_ero (K=128)
    f32x4 acc3[4][2];
#pragma unroll
    for (int m = 0; m < 4; ++m)
#pragma unroll
        for (int n = 0; n < 2; ++n) acc3[m][n] = 0.f;
#pragma unroll
    for (int ks = 0; ks < 4; ++ks) {
        const int k0 = ks * 32 + qk * 8;
        bf16x8 a[4], b[2];
#pragma unroll
        for (int m = 0; m < 4; ++m)
            a[m] = *reinterpret_cast<const bf16x8*>(sH + swz256(m * 16 + lr, k0 * 2));
#pragma unroll
        for (int n = 0; n < 2; ++n) b[n] = ld8(WeroT + col2[n] * D + k0);
#pragma unroll
        for (int m = 0; m < 4; ++m)
#pragma unroll
            for (int n = 0; n < 2; ++n) acc3[m][n] = mfma16(a[m], b[n], acc3[m][n]);
    }
#pragma unroll
    for (int n = 0; n < 2; ++n) {
        float bia = b_ero[col2[n]];
#pragma unroll
        for (int m = 0; m < 4; ++m) {
#pragma unroll
            for (int j = 0; j < 4; ++j) {
                int e = e0 + m * 16 + qk * 4 + j;
                e_ro[e * D + col2[n]] = acc3[m][n][j] + bia;
            }
        }
    }

    // logits: 2 outputs per edge, threads 0..127
    if (t < 128) {
        int el = t >> 1;
        int c  = t & 1;
        float s = 0.f;
#pragma unroll 8
        for (int k = 0; k < D; ++k) {
            float cv = (float)*reinterpret_cast<const bf16*>(sH + swz256(el, k * 2));
            s += cv * W_logit[k * 2 + c];
        }
        e_lg[(e0 + el) * 2 + c] = s + b_logit[c];
    }
}

// ---------------------------------------------------------------- launch
extern "C" void kernel_launch(void* const* d_in, const int* in_sizes, int n_in,
                              void* d_out, int out_size, void* d_ws, size_t ws_size,
                              hipStream_t stream) {
    const float* node_feat = (const float*)d_in[0];
    const int*   src       = (const int*)d_in[1];
    const int*   dst       = (const int*)d_in[2];
    const float* W_e1  = (const float*)d_in[3];
    const float* b_e1  = (const float*)d_in[4];
    const float* W_e2  = (const float*)d_in[5];
    const float* b_e2  = (const float*)d_in[6];
    const float* W_n1  = (const float*)d_in[7];
    const float* b_n1  = (const float*)d_in[8];
    const float* W_n2  = (const float*)d_in[9];
    const float* b_n2  = (const float*)d_in[10];
    const float* W_el1 = (const float*)d_in[11];
    const float* b_el1 = (const float*)d_in[12];
    const float* W_el2 = (const float*)d_in[13];
    const float* b_el2 = (const float*)d_in[14];
    const float* W_logit = (const float*)d_in[15];
    const float* b_logit = (const float*)d_in[16];
    const float* W_nro = (const float*)d_in[17];
    const float* b_nro = (const float*)d_in[18];
    const float* W_ero = (const float*)d_in[19];
    const float* b_ero = (const float*)d_in[20];

    char* ws = (char*)d_ws;
    bf16* nf_bf  = (bf16*)(ws);                     // 30000*128*2 = 7,680,000 B
    bf16* nf2_bf = (bf16*)(ws + 7680000);           // 7,680,000 B
    bf16* wblob  = (bf16*)(ws + 15360000);          // 720,896 B
    bf16* We1T  = wblob;              // [256][384]
    bf16* We2T  = We1T  + 98304;      // [128][256]
    bf16* Wn1T  = We2T  + 32768;      // [256][256]
    bf16* Wn2T  = Wn1T  + 65536;      // [128][256]
    bf16* Wel1T = Wn2T  + 32768;      // [256][256]
    bf16* Wel2T = Wel1T + 65536;      // [128][256]
    bf16* WnroT = Wel2T + 32768;      // [128][128]
    bf16* WeroT = WnroT + 16384;      // [128][128]

    float* out   = (float*)d_out;
    float* n_out = out;               // 3,840,000 f32
    float* e_ro  = out + 3840000;     // 76,800,000 f32
    float* e_lg  = out + 80640000;    // 1,200,000 f32
    // scratch overlays into d_out regions that are dead at time of use:
    float* hA = n_out;                // read by pass2, then overwritten by node kernel
    float* hB = e_ro;                 // read by node kernel, then overwritten by logits

    hipMemsetAsync(hA, 0, (size_t)NN * D * 4, stream);
    hipMemsetAsync(hB, 0, (size_t)NN * D * 4, stream);

    TPack pk;
    pk.m[0] = {W_e1,  We1T,  384, 256};
    pk.m[1] = {W_e2,  We2T,  256, 128};
    pk.m[2] = {W_n1,  Wn1T,  256, 256};
    pk.m[3] = {W_n2,  Wn2T,  256, 128};
    pk.m[4] = {W_el1, Wel1T, 256, 256};
    pk.m[5] = {W_el2, Wel2T, 256, 128};
    pk.m[6] = {W_nro, WnroT, 128, 128};
    pk.m[7] = {W_ero, WeroT, 128, 128};
    transpose_cast_kernel<<<dim3(8, 48), 256, 0, stream>>>(pk);
    cast_nf_kernel<<<(NN * D / 4 + 255) / 256, 256, 0, stream>>>(node_feat, nf_bf);

    edge_mlp_kernel<false><<<NE / 64, 256, 0, stream>>>(
        nf_bf, nullptr, src, dst, We1T, We2T, b_e1, b_e2, hA);
    edge_mlp_kernel<true><<<NE / 64, 256, 0, stream>>>(
        nf_bf, hA, src, dst, We1T, We2T, b_e1, b_e2, hB);

    node_mlp_kernel<<<(NN + 63) / 64, 256, 0, stream>>>(
        nf_bf, hB, Wn1T, Wn2T, WnroT, b_n1, b_n2, b_nro, nf2_bf, n_out);

    edge_logit_kernel<<<NE / 64, 256, 0, stream>>>(
        nf2_bf, src, dst, Wel1T, Wel2T, WeroT, W_logit,
        b_el1, b_el2, b_ero, b_logit, e_ro, e_lg);
}